// Round 1
// 440.283 us; speedup vs baseline: 1.0025x; 1.0025x over previous
//
#include <hip/hip_runtime.h>

// pose3d_future loss, round 5: cut per-wave serial time per tile.
// R4 structure kept: single-wave persistent blocks, 64-sample tiles,
// global_load_lds width=16 double buffer, manual vmcnt(27) pipelining,
// no barriers. Two changes, both targeting wave-busy time (theory: kernel
// is wave-busy-bound at ~10 B/cy/CU, not HBM-bound):
//  1) clamp-free split DMA for full tiles (B % 64 == 0 for B=1e6): pose and
//     est streams issued separately with base+r*NT addressing — same 27 vm
//     events (15 + 48-lane tail + 10 + 32-lane tail), ~2 VALU/load instead of
//     ~13 (64-bit clamps + pointer select). Clamped fallback (26+1 events,
//     also 27) only for a partial last tile.
//  2) register-stage each sample (63+42 floats) in unrolled straight-line
//     loads before computing: compiler merges adjacent dwords to ds_read2_b32
//     and hoists the whole LDS-load cluster ahead of the FMA chain, instead
//     of exposing per-joint load->use lgkm latency.

namespace {

constexpr float F_    = 525.0f;
constexpr float CX_   = 320.0f;
constexpr float CY_   = 240.0f;
constexpr float WPROJ = 0.33f / 42.0f;   // W_PROJ / (2*J)
constexpr float WBONE = 0.5f  / 20.0f;   // W_BONE / (J-1)
constexpr int   NT    = 64;              // one wave per block
constexpr int   TILE  = 64;              // samples per tile
constexpr int   PF4   = TILE * 63 / 4;   // 1008 float4 of pose per tile
constexpr int   EF4   = TILE * 42 / 4;   // 672  float4 of est  per tile
constexpr int   TF4   = PF4 + EF4;       // 1680 float4 per tile (26880 B)
// fast-path DMA rounds (full tiles):
constexpr int   PFULL = PF4 / NT;        // 15 full pose rounds
constexpr int   PREM  = PF4 - PFULL*NT;  // 48-lane pose tail
constexpr int   EFULL = EF4 / NT;        // 10 full est rounds
constexpr int   EREM  = EF4 - EFULL*NT;  // 32-lane est tail
constexpr int   DMA_N = PFULL + 1 + EFULL + 1;   // 27 vm events / tile
// slow-path (clamped) rounds — must also be 27 events:
constexpr int   RFULL = TF4 / NT;        // 26
constexpr int   REM   = TF4 - RFULL*NT;  // 16
static_assert(RFULL + 1 == DMA_N, "event counts must match");
constexpr int   NBLK  = 768;             // 3 single-wave blocks per CU

// gfx9/CDNA s_waitcnt imm: vmcnt[3:0]=b[3:0], vmcnt[5:4]=b[15:14],
// expcnt=b[6:4] (7=no wait), lgkmcnt=b[11:8] (15=no wait).
constexpr int wcnt(int vm, int lgkm) {
    return (vm & 0xF) | ((vm >> 4) << 14) | (0x7 << 4) | ((lgkm & 0xF) << 8);
}

__device__ __forceinline__ long lmin(long a, long b) { return a < b ? a : b; }

__device__ __forceinline__ void gload(const float4* g, float4* l) {
    __builtin_amdgcn_global_load_lds(
        (const __attribute__((address_space(1))) void*)g,
        (__attribute__((address_space(3))) void*)l, 16, 0, 0);
}

__global__ __launch_bounds__(NT)
void pose_loss_kernel(const float* __restrict__ pose,   // [B,3,21]
                      const float* __restrict__ est,    // [B,2,21]
                      const float* __restrict__ bl,     // [20]
                      const float* __restrict__ Rm,     // [3,3]
                      const float* __restrict__ Cd,     // [3,1]
                      float* __restrict__ out,
                      int B)
{
    __shared__ float4 smem[2 * TF4];     // 53760 B -> 3 blocks/CU

    const int tid = threadIdx.x;
    const float4* pose4 = (const float4*)pose;
    const float4* est4  = (const float4*)est;
    const long pmax = (long)B * 63 / 4 - 1;   // slow-path clamps
    const long emax = (long)B * 42 / 4 - 1;
    const int  ntiles    = (B + TILE - 1) / TILE;
    const int  fulltiles = B / TILE;          // tiles with no OOB risk

    // ---- uniform camera params: M = K @ R^T ----
    const float r0 = Rm[0], r1 = Rm[1], r2 = Rm[2];
    const float r3 = Rm[3], r4 = Rm[4], r5 = Rm[5];
    const float r6 = Rm[6], r7 = Rm[7], r8 = Rm[8];
    const float m00 = F_ * r0 + CX_ * r2;
    const float m01 = F_ * r3 + CX_ * r5;
    const float m02 = F_ * r6 + CX_ * r8;
    const float m10 = F_ * r1 + CY_ * r2;
    const float m11 = F_ * r4 + CY_ * r5;
    const float m12 = F_ * r7 + CY_ * r8;
    const float m20 = r2, m21 = r5, m22 = r8;
    const float c0 = Cd[0], c1 = Cd[1], c2 = Cd[2];
    float blv[20];
    #pragma unroll
    for (int i = 0; i < 20; ++i) blv[i] = bl[i];   // uniform -> SGPRs

    // ---- async DMA of one 64-sample tile into LDS buffer `buf` ----
    // Always issues exactly DMA_N=27 vm events (vmcnt arithmetic relies on it).
    auto dma = [&](long T, int buf) {
        float4* dst = &smem[buf * TF4];
        if (T < (long)fulltiles) {
            // fast path: no clamps, no pose/est select. Addresses are
            // per-lane base + compile-time r*NT.
            const float4* gp = pose4 + T * PF4 + tid;
            const float4* ge = est4  + T * EF4 + tid;
            #pragma unroll
            for (int r = 0; r < PFULL; ++r)
                gload(gp + r * NT, dst + r * NT);
            if (tid < PREM)                       // 48-lane pose tail
                gload(gp + PFULL * NT, dst + PFULL * NT);
            #pragma unroll
            for (int r = 0; r < EFULL; ++r)
                gload(ge + r * NT, dst + PF4 + r * NT);
            if (tid < EREM)                       // 32-lane est tail
                gload(ge + EFULL * NT, dst + PF4 + EFULL * NT);
        } else {
            // slow path (partial last tile): clamped per-load select.
            const long pb = T * PF4;
            const long eb = T * EF4 - PF4;        // so est idx = eb + f
            #pragma unroll
            for (int r = 0; r < RFULL; ++r) {
                const int f = r * NT + tid;
                const float4* g = (f < PF4) ? (pose4 + lmin(pb + f, pmax))
                                            : (est4  + lmin(eb + f, emax));
                gload(g, dst + r * NT);
            }
            if (tid < REM) {
                const long gi = lmin(eb + RFULL * NT + tid, emax);
                gload(est4 + gi, dst + RFULL * NT);
            }
        }
    };

    float accP = 0.0f, accB = 0.0f;
    long T = blockIdx.x;
    if (T < ntiles) dma(T, 0);

    int i = 0;
    while (T < ntiles) {
        const long Tn = T + NBLK;
        __asm__ __volatile__("" ::: "memory");
        // my ds_reads of the buffer about to be overwritten are retired (all
        // staged values were consumed); belt-and-braces lgkm drain anyway.
        __builtin_amdgcn_s_waitcnt(wcnt(63, 0));
        if (Tn < ntiles) {
            dma(Tn, (i + 1) & 1);                          // +27 in flight
            __builtin_amdgcn_s_waitcnt(wcnt(DMA_N, 15));   // tile T landed,
        } else {                                           // tile Tn still flying
            __builtin_amdgcn_s_waitcnt(wcnt(0, 15));       // tail: full drain
        }
        __asm__ __volatile__("" ::: "memory");

        // ---- compute tile T from LDS buffer i&1 (1 thread : 1 sample) ----
        const float* sm = (const float*)&smem[(i & 1) * TF4];
        const float* ps = sm + tid * 63;             // x0..20 y0..20 z0..20
        const float* es = sm + TILE * 63 + tid * 42; // u0..20 v0..20

        // register-stage the whole sample: straight-line loads the compiler
        // can merge (ds_read2_b32) and hoist ahead of the FMA chain.
        float P[63], E[42];
        #pragma unroll
        for (int k = 0; k < 63; ++k) P[k] = ps[k];
        #pragma unroll
        for (int k = 0; k < 42; ++k) E[k] = es[k];

        const bool valid = (T * TILE + tid) < (long)B;
        float proj = 0.0f, bone = 0.0f;
        float pvx = 0.f, pvy = 0.f, pvz = 0.f;
        #pragma unroll
        for (int j = 0; j < 21; ++j) {
            const float x = P[j]      - c0;
            const float y = P[21 + j] - c1;
            const float z = P[42 + j] - c2;
            const float q0 = fmaf(m00, x, fmaf(m01, y, m02 * z));
            const float q1 = fmaf(m10, x, fmaf(m11, y, m12 * z));
            const float q2 = fmaf(m20, x, fmaf(m21, y, m22 * z));
            const float inv = __builtin_amdgcn_rcpf(q2);   // z ~ 10, safe
            const float du = fmaf(q0, inv, -E[j]);
            const float dv = fmaf(q1, inv, -E[21 + j]);
            proj += du * du + dv * dv;
            if (j > 0) {                 // chain bone (j-1, j); C cancels
                const float dx = pvx - x, dy = pvy - y, dz = pvz - z;
                const float sq = dx * dx + dy * dy + dz * dz;
                const float e  = blv[j - 1] - sq;
                bone += e * e;
            }
            pvx = x; pvy = y; pvz = z;
        }
        accP += valid ? proj : 0.0f;     // select also kills tail NaN/inf
        accB += valid ? bone : 0.0f;

        T = Tn; ++i;
    }

    // ---- wave reduction + one atomic per block ----
    float acc = WPROJ * accP + WBONE * accB;
    #pragma unroll
    for (int off = 32; off > 0; off >>= 1)
        acc += __shfl_down(acc, off, 64);
    if (tid == 0)
        atomicAdd(out, acc * (1.0f / (float)B));
}

} // namespace

extern "C" void kernel_launch(void* const* d_in, const int* in_sizes, int n_in,
                              void* d_out, int out_size, void* d_ws, size_t ws_size,
                              hipStream_t stream) {
    const float* pose = (const float*)d_in[0];
    const float* est  = (const float*)d_in[1];
    const float* bl   = (const float*)d_in[2];
    const float* Rm   = (const float*)d_in[3];
    const float* Cd   = (const float*)d_in[4];
    float* out = (float*)d_out;

    const int B = in_sizes[0] / 63;               // [B,3,21] flat

    hipMemsetAsync(out, 0, sizeof(float), stream);  // d_out is poisoned 0xAA
    pose_loss_kernel<<<NBLK, NT, 0, stream>>>(pose, est, bl, Rm, Cd, out, B);
}